// Round 7
// baseline (14.437 us; speedup 1.0000x reference)
//
#include <hip/hip_runtime.h>

namespace {
constexpr int R = 16;

__device__ __forceinline__ float rdlanef(float v, int lane) {
    return __int_as_float(__builtin_amdgcn_readlane(__float_as_int(v), lane));
}
__device__ __forceinline__ int rdlanei(float v, int lane) {
    return __builtin_amdgcn_readlane(__float_as_int(v), lane);
}
__device__ __forceinline__ float bpermf(float v, int srclane) {
    return __int_as_float(__builtin_amdgcn_ds_bpermute(srclane * 4, __float_as_int(v)));
}
__device__ __forceinline__ int bpermi(int v, int srclane) {
    return __builtin_amdgcn_ds_bpermute(srclane * 4, v);
}
}

// Single fused kernel. Each WAVE redundantly computes prep (~220 instrs, no
// barriers, wave-synchronous): stable ranks via bpermute, permutation invert
// via one ds_permute push, per-lane frb loads + transforms. Rule p's params
// live in lane p's VGPRs (pr0..pr15); pass-2 scan tables in lanes 16..31.
// Hot loop streams them with v_readlane (constant lane -> SGPR; each fma uses
// exactly 1 SGPR operand). NO second dispatch, NO param LDS traffic.
// __launch_bounds__(256,4): 4 waves/EU min => VGPR capped at 128 => the
// grid's 4 blocks/CU are guaranteed co-resident (occupancy probe vs R6).
__global__ __launch_bounds__(256, 4) void t2fls_fused(
    const float* __restrict__ x,
    const float* __restrict__ frb,
    const float* __restrict__ c1g,
    const float* __restrict__ c2g,
    float* __restrict__ out)
{
    __shared__ float dls[R][256];          // d-permutation column file (16 KB)
    const int tid  = threadIdx.x;
    const int gid  = blockIdx.x * 256 + tid;
    const float4 xv = reinterpret_cast<const float4*>(x)[gid];   // issue early

    const int lane = tid & 63;
    const int sub  = lane & 15;            // position within 16-group
    const int p2   = (lane >> 4) & 1;      // 0: c1 pass, 1: c2 pass
    const int quad = lane & 48;            // duplicate quadrants (32-63 mirror 0-31)

    // ---- per-wave prep ----------------------------------------------------
    const float ci = (p2 ? c2g : c1g)[sub];          // own c value
    int rank = 0;
    #pragma unroll
    for (int j = 0; j < R; ++j) {
        const float cj = bpermf(ci, p2 * 16 + j);    // c_pass[j]
        rank += (cj < ci || (cj == ci && j < sub)) ? 1 : 0;   // stable argsort
    }
    // invert: lane (quad|rank) receives i = idx_pass[rank]
    const int i = __builtin_amdgcn_ds_permute((quad + rank) * 4, sub);

    // cross-lane coefficient pulls (src lanes 0..31 hold real data)
    const float c1s = bpermf(ci, i);                 // c1[idx1[p]]   (group0 use)
    const float c2p = bpermf(ci, 16 + i);            // c2[i]: group0 c2[idx1[p]], group1 c2s[k]
    const int   r2i = bpermi(rank, 16 + i);          // rk2[i]        (group0 use)
    const float c2m = bpermf(ci, 16 + r2i);          // c2[rk2[idx1[p]]] (ref mispair)
    const int   r1i = bpermi(rank, i);               // rk1[i]: group1 -> rk1[idx2[k]]
    const int pioff = r1i << 10;                     // dls row byte offset (256*4)

    // per-lane rule load + Gaussian transforms (group1 lanes waste this, fine)
    const float* fb = frb + i * 12;                  // 48B-aligned -> float4 ok
    const float4 f0 = *reinterpret_cast<const float4*>(fb);
    const float4 f1 = *reinterpret_cast<const float4*>(fb + 4);
    const float4 f2 = *reinterpret_cast<const float4*>(fb + 8);
    // layout: rule i, antecedent a: [i*12 + a*3 + {m,s1,s2}]
    const float HL2E = 0.7213475204444817f;          // 0.5*log2(e)
    float mm[4], kh[4], kl[4];
    {
        const float m_[4]  = {f0.x, f0.w, f1.z, f2.y};
        const float s1_[4] = {f0.y, f1.x, f1.w, f2.z};
        const float s2_[4] = {f0.z, f1.y, f2.x, f2.w};
        #pragma unroll
        for (int a = 0; a < 4; ++a) {
            const float slo = fminf(s1_[a], s2_[a]);
            const float shi = fmaxf(s1_[a], s2_[a]);
            mm[a] = m_[a];
            kh[a] = -HL2E * __builtin_amdgcn_rcpf(shi * shi);
            kl[a] = -HL2E * __builtin_amdgcn_rcpf(slo * slo);
        }
    }
    // param register file: lane p -> rule p (group0); lane 16+k -> scan tables
    const bool g1 = (lane & 16) != 0;
    const float pr0  = g1 ? __int_as_float(pioff) : mm[0];
    const float pr1  = mm[1], pr2 = mm[2], pr3 = mm[3];
    const float pr4  = kh[0], pr5 = kh[1], pr6 = kh[2], pr7 = kh[3];
    const float pr8  = kl[0], pr9 = kl[1], pr10 = kl[2], pr11 = kl[3];
    const float pr12 = c1s;   // c1 sorted
    const float pr13 = ci;    // own c: group0 c1[p] (mispair), group1 c2[k]
    const float pr14 = c2p;   // group0 c2[idx1[p]], group1 c2[idx2[k]]
    const float pr15 = c2m;   // group0 mispaired c2

    // ---- membership + base sums (idx1 order), d into regs + LDS column ----
    float d1[R];
    float s0L = 0.f, t0L = 0.f, suL = 0.f;
    float s0R = 0.f, t0R = 0.f, suR = 0.f;
    #pragma unroll
    for (int p = 0; p < R; ++p) {
        const float z0 = xv.x - rdlanef(pr0, p);
        const float z1 = xv.y - rdlanef(pr1, p);
        const float z2 = xv.z - rdlanef(pr2, p);
        const float z3 = xv.w - rdlanef(pr3, p);
        const float q0 = z0 * z0, q1 = z1 * z1, q2 = z2 * z2, q3 = z3 * z3;
        float eU = rdlanef(pr4, p) * q0;
        eU = fmaf(rdlanef(pr5, p), q1, eU);
        eU = fmaf(rdlanef(pr6, p), q2, eU);
        eU = fmaf(rdlanef(pr7, p), q3, eU);
        float eL = rdlanef(pr8, p) * q0;
        eL = fmaf(rdlanef(pr9, p), q1, eL);
        eL = fmaf(rdlanef(pr10, p), q2, eL);
        eL = fmaf(rdlanef(pr11, p), q3, eL);
        const float uu = __builtin_amdgcn_exp2f(eU);   // prod_a mu_hi
        const float ll = __builtin_amdgcn_exp2f(eL);   // prod_a mu_lo
        s0L = fmaf(rdlanef(pr12, p), ll, s0L);
        t0L += ll;
        suL = fmaf(rdlanef(pr13, p), ll, suL);
        s0R = fmaf(rdlanef(pr14, p), uu, s0R);
        t0R += uu;
        suR = fmaf(rdlanef(pr15, p), uu, suR);
        const float dv = uu - ll;                      // dv >= 0
        d1[p] = dv;
        dls[p][tid] = dv;                              // imm-offset ds_write_b32
    }

    // ---- left endpoint: scan in idx1 order (registers) --------------------
    float left;
    {
        float ss = fmaf(rdlanef(pr12, 0), d1[0], s0L);
        float tt = t0L + d1[0];
        float cn = rdlanef(pr13, 0) * d1[0];
        float sb = ss, tb = tt, cnb = cn;
        const float tt0 = tt, cn0 = cn;
        #pragma unroll
        for (int k = 1; k < R; ++k) {
            ss = fmaf(rdlanef(pr12, k), d1[k], ss);
            tt += d1[k];
            cn = fmaf(rdlanef(pr13, k), d1[k], cn);
            if ((ss * tb) < (sb * tt)) { sb = ss; tb = tt; cnb = cn; }  // first-occ argmin
        }
        if ((s0L * tb) <= (sb * t0L)) { tb = tt0; cnb = cn0; }  // q0 dominates -> loc 0
        left = (suL + cnb) * __builtin_amdgcn_rcpf(tb);
    }

    // ---- right endpoint: idx2-permuted d via per-thread LDS column --------
    float dv[R];
    const char* colbase = reinterpret_cast<const char*>(&dls[0][tid]);
    #pragma unroll
    for (int k = 0; k < R; ++k) {
        const int off = rdlanei(pr0, 16 + k);          // rk1[idx2[k]]*1024 (SGPR)
        dv[k] = *reinterpret_cast<const float*>(colbase + off);
    }
    float right;
    {
        // dr[k] = -dv[k]; signs folded via negated SGPR operands
        float ss = fmaf(-rdlanef(pr14, 16), dv[0], s0R);
        float tt = t0R - dv[0];
        float cn = -rdlanef(pr13, 16) * dv[0];
        float sb = ss, tb = tt, cnb = cn;
        const float tt0 = tt, cn0 = cn;
        #pragma unroll
        for (int k = 1; k < R; ++k) {
            ss = fmaf(-rdlanef(pr14, 16 + k), dv[k], ss);
            tt -= dv[k];
            cn = fmaf(-rdlanef(pr13, 16 + k), dv[k], cn);
            if ((ss * tb) > (sb * tt)) { sb = ss; tb = tt; cnb = cn; }  // first-occ argmax
        }
        if ((s0R * tb) >= (sb * t0R)) { tb = tt0; cnb = cn0; }  // q0 dominates -> loc 0
        right = (suR + cnb) * __builtin_amdgcn_rcpf(tb);
    }

    out[gid] = 0.5f * (left + right);
}

extern "C" void kernel_launch(void* const* d_in, const int* in_sizes, int n_in,
                              void* d_out, int out_size, void* d_ws, size_t ws_size,
                              hipStream_t stream) {
    const float* x   = (const float*)d_in[0];   // (N, 4) float32
    const float* frb = (const float*)d_in[1];   // (R*A*3,) float32
    const float* c1  = (const float*)d_in[2];   // (R,) float32
    const float* c2  = (const float*)d_in[3];   // (R,) float32
    float* out = (float*)d_out;                 // (N,) float32

    const int n = out_size;                     // N = 262144 (multiple of 256)
    hipLaunchKernelGGL(t2fls_fused, dim3(n / 256), dim3(256), 0, stream,
                       x, frb, c1, c2, out);
}